// Round 14
// baseline (979.135 us; speedup 1.0000x reference)
//
#include <hip/hip_runtime.h>
#include <hip/hip_bf16.h>
#include <hip/hip_cooperative_groups.h>

namespace cg = cooperative_groups;

#define BB 32
#define LL 64
#define EE 1024
#define HH 128
#define VV 32000

typedef unsigned short u16;
typedef unsigned long long u64;
typedef __attribute__((ext_vector_type(8))) short bf16x8;
typedef __attribute__((ext_vector_type(8))) unsigned short u16x8;
typedef __attribute__((ext_vector_type(4))) float f32x4;

#define LOG2E 1.4426950408889634f
#define C2T   2.8853900817779268f   // 2*log2(e)

// output element offsets (return order: logits, c_fin, h_fin, alphas)
#define OFF_C ((size_t)BB * LL * VV)
#define OFF_H (OFF_C + (size_t)BB * HH)
#define OFF_A (OFF_H + (size_t)BB * HH)

// ws byte offsets
#define WS_ENCT 0                    // 8,388,608 B u16 encT [b][h][e] C2T-prescaled
#define WS_HS   ((size_t)8388608)    // 524,288 B bf16
#define WS_GX   ((size_t)8912896)    // 4,194,304 B f32
#define WS_PAYU ((size_t)13107200)   // 532,480 B u64 [32][8][2][130]
#define WS_PAYG ((size_t)13639680)   // 262,144 B u64 [32][8][2][64]
#define WS_NEED ((size_t)13901824)

__device__ __forceinline__ float bf2f(u16 u) {
    union { unsigned int i; float f; } v; v.i = ((unsigned int)u) << 16; return v.f;
}
__device__ __forceinline__ u16 f2bf(float f) {
    union { float f; unsigned int i; } v; v.f = f;
    unsigned int x = v.i;
    return (u16)((x + 0x7FFFu + ((x >> 16) & 1u)) >> 16);
}
__device__ __forceinline__ float ldf(const void* p, size_t i, int f32) {
    if (f32) return ((const float*)p)[i];
    return bf2f(((const u16*)p)[i]);
}
__device__ __forceinline__ void stout(void* p, size_t i, float v, int f32) {
    if (f32) ((float*)p)[i] = v;
    else ((u16*)p)[i] = f2bf(v);
}
__device__ __forceinline__ float sigm(float x) {
    return __builtin_amdgcn_rcpf(1.f + __builtin_amdgcn_exp2f(-x * LOG2E));
}
__device__ __forceinline__ float tanh_fast(float x) {
    return 1.f - 2.f * __builtin_amdgcn_rcpf(__builtin_amdgcn_exp2f(x * C2T) + 1.f);
}

// ============ ONE fused cooperative kernel: prep + scan + logits ==========
// 256 blocks x 1024 threads (1 block/CU). Two grid syncs separate phases.
// Scan body is byte-identical to round 13 (reproduced 531-541 us twice).
__global__ __launch_bounds__(1024) void fused_kernel(
    const int* __restrict__ sent, const void* __restrict__ w_emb,
    const void* __restrict__ w_lstm, const void* __restrict__ enc_out,
    const void* __restrict__ V, const void* __restrict__ w_soft,
    const void* __restrict__ init_c, const void* __restrict__ init_h,
    float* __restrict__ gx, u16* __restrict__ encTg16, u16* __restrict__ hs_bf,
    void* __restrict__ out, u64* __restrict__ payu, u64* __restrict__ payg)
{
    const int bid = blockIdx.x;
    const int b = bid & 31, k = bid >> 5;      // 8 partners per batch
    const int tid = threadIdx.x;

    __shared__ u16   encTl16[128][128];        // 32KB bf16 [h][e] (prologue: unused)
    __shared__ float encF[128][128];           // 64KB f32 [e][h]  (prologue: ve)
    __shared__ u16   wrec16[64 * 128];         // 16KB bf16        (prologue: xr)
    __shared__ float gall[512];
    __shared__ float harr[128], cst[128], hnew[128], hvC[128];
    __shared__ float dred[8][128];
    __shared__ float sc[128];
    __shared__ float exch[8][130];
    __shared__ float redw[2], redw2[2];
    __shared__ float m_s, s_s;
    __shared__ int dcnt[4];

    // ======== PROLOGUE ========
    // detect dtype (proven ballot method)
    if (tid < 256) {
        float a = fabsf(bf2f((u16)(((const unsigned int*)w_emb)[tid] & 0xFFFFu)));
        unsigned long long m = __ballot(a > 1e-4f && a < 0.5f);
        if ((tid & 63) == 0) dcnt[tid >> 6] = __popcll(m);
    }
    __syncthreads();
    const int isf32 = !(dcnt[0] + dcnt[1] + dcnt[2] + dcnt[3] > 128);

    // zero own payload region (replay/ABA safety; partners read after sync)
    u64* mypu = payu + (size_t)(b * 8 + k) * 2 * 130;
    u64* mypg = payg + (size_t)(b * 8 + k) * 2 * 64;
    if (tid < 260) mypu[tid] = 0ull;
    else if (tid < 260 + 128) mypg[tid - 260] = 0ull;

    // gx role: 8 sentence-rows per block (same FMA order as round 13)
    {
        float (*xr)[128] = (float(*)[128])wrec16;
        int row0 = bid * 8;
        {
            int r = tid >> 7, col = tid & 127;
            int id = sent[row0 + r];
            xr[r][col] = ldf(w_emb, (size_t)id * HH + col, isf32);
        }
        __syncthreads();
        int c = tid & 511, rh = tid >> 9;
        float a4[4] = {0.f, 0.f, 0.f, 0.f};
        for (int kk = 0; kk < 128; ++kk) {
            float wv = ldf(w_lstm, (size_t)kk * 512 + c, isf32);
            #pragma unroll
            for (int r = 0; r < 4; ++r)
                a4[r] += xr[rh * 4 + r][kk] * wv;
        }
        #pragma unroll
        for (int r = 0; r < 4; ++r)
            gx[(size_t)(row0 + rh * 4 + r) * 512 + c] = a4[r];
    }
    __syncthreads();
    // encproj role: 2 (batch, e-64-range) units per block
    {
        float (*ve)[128] = (float(*)[128])encF;
        for (int i = tid; i < HH * HH; i += 1024)
            ve[i >> 7][i & 127] = ldf(V, i, isf32);
        __syncthreads();
        #pragma unroll
        for (int u = 0; u < 2; ++u) {
            int unit = bid * 2 + u;
            int bb = unit >> 4;
            int e0 = (unit & 15) * 64;
            int e = e0 + (tid & 63);
            int h0 = (tid >> 6) * 8;
            size_t rowbase = ((size_t)bb * EE + e) * HH;
            float acc[8];
            #pragma unroll
            for (int i = 0; i < 8; ++i) acc[i] = 0.f;
            for (int k0 = 0; k0 < HH; k0 += 16) {
                float ef[16];
                #pragma unroll
                for (int i = 0; i < 16; ++i) ef[i] = ldf(enc_out, rowbase + k0 + i, isf32);
                #pragma unroll
                for (int hh = 0; hh < 8; ++hh) {
                    float a = acc[hh];
                    #pragma unroll
                    for (int kk = 0; kk < 16; ++kk)
                        a += ef[kk] * ve[k0 + kk][h0 + hh];
                    acc[hh] = a;
                }
            }
            u16* outp = encTg16 + ((size_t)bb * HH) * EE + e;
            #pragma unroll
            for (int hh = 0; hh < 8; ++hh)
                outp[(size_t)(h0 + hh) * EE] = f2bf(acc[hh] * C2T);
        }
    }
    __threadfence();
    cg::this_grid().sync();                    // ---- grid barrier #1 ----

    // ======== STAGING (identical to round 13) ========
    for (int i = tid; i < 128 * 128; i += 1024) {
        int h = i >> 7, e = i & 127;
        encTl16[h][e] = encTg16[(size_t)(b * 128 + h) * EE + k * 128 + e];
    }
    for (int i = tid; i < 128 * 128; i += 1024) {
        int e = i >> 7, hh = i & 127;
        encF[e][hh] = ldf(enc_out, ((size_t)b * EE + k * 128 + e) * HH + hh, isf32);
    }
    for (int i = tid; i < 64 * 128; i += 1024) {
        int c = i >> 7, kk = i & 127;
        wrec16[c * 128 + kk] = f2bf(ldf(w_lstm, (size_t)(HH + kk) * 512 + k * 64 + c, isf32));
    }
    if (tid < 128) {
        cst[tid]  = ldf(init_c, (size_t)b * HH + tid, isf32);
        harr[tid] = ldf(init_h, (size_t)b * HH + tid, isf32);
    }
    __syncthreads();

    // ======== SCAN LOOP (byte-identical round-13 body) ========
    for (int t = 0; t < LL; ++t) {
        const unsigned int want = (unsigned int)(t + 1);
        float g0 = 0.f, g1 = 0.f, g2 = 0.f, g3 = 0.f;
        if (tid < 128) {
            const float* gxr = gx + (size_t)(b * LL + t) * 512;
            g0 = gxr[tid]; g1 = gxr[128 + tid]; g2 = gxr[256 + tid]; g3 = gxr[384 + tid];
        }
        // A: this block's 64 gate cols; 16 lanes per col, shfl butterfly
        {
            int colL = tid >> 4, kc = tid & 15;
            const bf16x8 wv = *(const bf16x8*)&wrec16[colL * 128 + kc * 8];
            float acc = 0.f;
            #pragma unroll
            for (int j = 0; j < 8; ++j)
                acc = __builtin_fmaf(harr[kc * 8 + j], bf2f((u16)wv[j]), acc);
            acc += __shfl_xor(acc, 1);
            acc += __shfl_xor(acc, 2);
            acc += __shfl_xor(acc, 4);
            acc += __shfl_xor(acc, 8);
            if (kc == 0) {
                gall[(k << 6) + colL] = acc;
                union { float f; unsigned int u; } cv; cv.f = acc;
                u64 w = ((u64)want << 32) | (u64)cv.u;
                __hip_atomic_store(&mypg[(size_t)(t & 1) * 64 + colL], w,
                                   __ATOMIC_RELAXED, __HIP_MEMORY_SCOPE_AGENT);
            }
        }
        if (tid < 448) {
            int qq = tid >> 6;
            int q = qq + (qq >= k ? 1 : 0);
            int idx = tid & 63;
            const u64* qp = payg + ((size_t)(b * 8 + q) * 2 + (t & 1)) * 64 + idx;
            u64 w = __hip_atomic_load(qp, __ATOMIC_RELAXED, __HIP_MEMORY_SCOPE_AGENT);
            int cnt = 0;
            while ((unsigned int)(w >> 32) != want) {
                __builtin_amdgcn_s_sleep(1);
                w = __hip_atomic_load(qp, __ATOMIC_RELAXED, __HIP_MEMORY_SCOPE_AGENT);
                if (++cnt > (1 << 20)) break;   // fail visibly, never hang
            }
            union { unsigned int u; float f; } cv; cv.u = (unsigned int)(w & 0xFFFFFFFFu);
            gall[q * 64 + idx] = cv.f;
        }
        __syncthreads();                                   // (1)
        if (tid < 128) {
            float gi = g0 + gall[tid];
            float gf = g1 + gall[128 + tid];
            float go = g2 + gall[256 + tid];
            float gg = g3 + gall[384 + tid];
            float c_new = sigm(gf) * cst[tid] + sigm(gi) * tanh_fast(gg);
            cst[tid] = c_new;
            hnew[tid] = sigm(go) * tanh_fast(c_new);
        }
        __syncthreads();                                   // (2)
        // C: hv[h] = h_new . V_h[:,h] (L2-hot, shared by whole XCD)
        {
            int h = tid & 127, jc = tid >> 7;
            float p = 0.f;
            if (isf32) {
                const float* vp = (const float*)V + (size_t)(HH + jc * 16) * HH + h;
                #pragma unroll
                for (int j = 0; j < 16; ++j)
                    p += hnew[jc * 16 + j] * vp[(size_t)j * HH];
            } else {
                const u16* vp = (const u16*)V + (size_t)(HH + jc * 16) * HH + h;
                #pragma unroll
                for (int j = 0; j < 16; ++j)
                    p += hnew[jc * 16 + j] * bf2f(vp[(size_t)j * HH]);
            }
            dred[jc][h] = p;
        }
        __syncthreads();                                   // (3)
        if (tid < 128) {
            float v = 0.f;
            #pragma unroll
            for (int s = 0; s < 8; ++s) v += dred[s][tid];
            hvC[tid] = v * C2T;
        }
        __syncthreads();                                   // (4)
        // D: partial tanh sums over own 128-e slice (LDS bf16)
        {
            int e = tid & 127, hc = tid >> 7;
            float sumr = 0.f;
            #pragma unroll
            for (int j = 0; j < 16; ++j) {
                int h = hc * 16 + j;
                float a = bf2f(encTl16[h][e]) + hvC[h];
                sumr += __builtin_amdgcn_rcpf(__builtin_amdgcn_exp2f(a) + 1.f);
            }
            dred[hc][e] = sumr;
        }
        __syncthreads();                                   // (5)
        // E: local scores + local softmax stats
        float s_e = 0.f, p_reg = 0.f;
        if (tid < 128) {
            float sr = 0.f;
            #pragma unroll
            for (int s = 0; s < 8; ++s) sr += dred[s][tid];
            s_e = 128.f - 2.f * sr;
            float m = s_e;
            #pragma unroll
            for (int off = 32; off; off >>= 1) m = fmaxf(m, __shfl_xor(m, off));
            if ((tid & 63) == 0) redw[tid >> 6] = m;
        }
        __syncthreads();                                   // (6)
        if (tid < 128) {
            float mloc = fmaxf(redw[0], redw[1]);
            p_reg = __builtin_amdgcn_exp2f((s_e - mloc) * LOG2E);
            sc[tid] = p_reg;
            float s = p_reg;
            #pragma unroll
            for (int off = 32; off; off >>= 1) s += __shfl_xor(s, off);
            if ((tid & 63) == 0) redw2[tid >> 6] = s;
            if (tid == 0) m_s = mloc;
        }
        __syncthreads();                                   // (7)
        if (tid == 0) s_s = redw2[0] + redw2[1];
        // F: partial unnormalized context from LDS enc slice (f32, exact)
        {
            int h = tid & 127, ec = tid >> 7;
            float p = 0.f;
            #pragma unroll
            for (int j = 0; j < 16; ++j)
                p += sc[ec * 16 + j] * encF[ec * 16 + j][h];
            dred[ec][h] = p;
        }
        __syncthreads();                                   // (8)
        float Uv = 0.f;
        if (tid < 128) {
            #pragma unroll
            for (int s = 0; s < 8; ++s) Uv += dred[s][tid];
        }
        {
            u64* pp = mypu + (size_t)(t & 1) * 130;
            if (tid < 130) {
                float val = (tid < 128) ? Uv : ((tid == 128) ? m_s : s_s);
                union { float f; unsigned int u; } cv; cv.f = val;
                u64 w = ((u64)want << 32) | (u64)cv.u;
                __hip_atomic_store(&pp[tid], w, __ATOMIC_RELAXED, __HIP_MEMORY_SCOPE_AGENT);
                exch[k][tid] = val;
            }
        }
        if (tid < 910) {
            int qq = tid / 130;
            int q = qq + (qq >= k ? 1 : 0);
            int idx = tid - qq * 130;
            const u64* qp = payu + ((size_t)(b * 8 + q) * 2 + (t & 1)) * 130 + idx;
            u64 w = __hip_atomic_load(qp, __ATOMIC_RELAXED, __HIP_MEMORY_SCOPE_AGENT);
            int cnt = 0;
            while ((unsigned int)(w >> 32) != want) {
                __builtin_amdgcn_s_sleep(1);
                w = __hip_atomic_load(qp, __ATOMIC_RELAXED, __HIP_MEMORY_SCOPE_AGENT);
                if (++cnt > (1 << 20)) break;   // fail visibly, never hang
            }
            union { unsigned int u; float f; } cv; cv.u = (unsigned int)(w & 0xFFFFFFFFu);
            exch[q][idx] = cv.f;
        }
        __syncthreads();                                   // (9)
        if (tid < 128) {
            float M = exch[0][128];
            #pragma unroll
            for (int q = 1; q < 8; ++q) M = fmaxf(M, exch[q][128]);
            float St = 0.f, ch = 0.f;
            #pragma unroll
            for (int q = 0; q < 8; ++q) {
                float w = __builtin_amdgcn_exp2f((exch[q][128] - M) * LOG2E);
                St += w * exch[q][129];
                ch += w * exch[q][tid];
            }
            float rS = __builtin_amdgcn_rcpf(St);
            float ctx = ch * rS;
            harr[tid] = ctx;
            float al = p_reg * __builtin_amdgcn_exp2f((m_s - M) * LOG2E) * rS;
            stout(out, OFF_A + (size_t)(b * LL + t) * EE + k * 128 + tid, al, isf32);
            if (k == 0) {
                hs_bf[(size_t)(b * LL + t) * HH + tid] = f2bf(ctx);
                if (t == LL - 1) {
                    stout(out, OFF_H + (size_t)b * HH + tid, ctx, isf32);
                    stout(out, OFF_C + (size_t)b * HH + tid, cst[tid], isf32);
                }
            }
        }
        __syncthreads();                                   // (10)
    }

    __threadfence();
    cg::this_grid().sync();                    // ---- grid barrier #2 ----

    // ======== LOGITS: hs @ w_soft, direct-B (no transpose) ========
    {
        const int wgl = bid * 16 + (tid >> 6);        // wave 0..4095
        const int lane = tid & 63;
        const int lr = lane & 15, lh = lane >> 4;
        for (int task = wgl; task < 64000; task += 4096) {
            int nx = task >> 6, my = task & 63;
            int n0 = nx * 32, m0 = my * 32;
            f32x4 acc00 = {0.f, 0.f, 0.f, 0.f}, acc01 = acc00, acc10 = acc00, acc11 = acc00;
            const u16* a0p = hs_bf + (size_t)(m0 + lr) * HH + lh * 8;
            const u16* a1p = a0p + (size_t)16 * HH;
            #pragma unroll
            for (int ks = 0; ks < 4; ++ks) {
                bf16x8 a0 = *(const bf16x8*)(a0p + ks * 32);
                bf16x8 a1 = *(const bf16x8*)(a1p + ks * 32);
                bf16x8 b0, b1;
                #pragma unroll
                for (int j = 0; j < 8; ++j) {
                    int kk = ks * 32 + lh * 8 + j;
                    b0[j] = (short)f2bf(ldf(w_soft, (size_t)kk * VV + n0 + lr, isf32));
                    b1[j] = (short)f2bf(ldf(w_soft, (size_t)kk * VV + n0 + 16 + lr, isf32));
                }
                acc00 = __builtin_amdgcn_mfma_f32_16x16x32_bf16(a0, b0, acc00, 0, 0, 0);
                acc01 = __builtin_amdgcn_mfma_f32_16x16x32_bf16(a0, b1, acc01, 0, 0, 0);
                acc10 = __builtin_amdgcn_mfma_f32_16x16x32_bf16(a1, b0, acc10, 0, 0, 0);
                acc11 = __builtin_amdgcn_mfma_f32_16x16x32_bf16(a1, b1, acc11, 0, 0, 0);
            }
            size_t base0 = (size_t)(m0 + lh * 4) * VV + n0;
            size_t base1 = (size_t)(m0 + 16 + lh * 4) * VV + n0;
            #pragma unroll
            for (int r = 0; r < 4; ++r) {
                stout(out, base0 + (size_t)r * VV + lr,      acc00[r], isf32);
                stout(out, base0 + (size_t)r * VV + 16 + lr, acc01[r], isf32);
                stout(out, base1 + (size_t)r * VV + lr,      acc10[r], isf32);
                stout(out, base1 + (size_t)r * VV + 16 + lr, acc11[r], isf32);
            }
        }
    }
}

extern "C" void kernel_launch(void* const* d_in, const int* in_sizes, int n_in,
                              void* d_out, int out_size, void* d_ws, size_t ws_size,
                              hipStream_t stream)
{
    (void)in_sizes; (void)n_in; (void)out_size;
    if (ws_size < WS_NEED) return;

    const int* sent     = (const int*)d_in[0];
    const void* init_c  = d_in[1];
    const void* init_h  = d_in[2];
    const void* enc_out = d_in[3];
    const void* w_emb   = d_in[4];
    const void* w_lstm  = d_in[5];
    const void* w_soft  = d_in[6];
    const void* V       = d_in[7];

    char* ws = (char*)d_ws;
    u16*   encT  = (u16*)(ws + WS_ENCT);
    u16*   hs    = (u16*)(ws + WS_HS);
    float* gx    = (float*)(ws + WS_GX);
    u64*   payu  = (u64*)(ws + WS_PAYU);
    u64*   payg  = (u64*)(ws + WS_PAYG);

    const int* a0 = sent; const void* a1 = w_emb; const void* a2 = w_lstm;
    const void* a3 = enc_out; const void* a4 = V; const void* a5 = w_soft;
    const void* a6 = init_c; const void* a7 = init_h;
    float* a8 = gx; u16* a9 = encT; u16* a10 = hs; void* a11 = d_out;
    u64* a12 = payu; u64* a13 = payg;
    void* args[] = {&a0, &a1, &a2, &a3, &a4, &a5, &a6, &a7,
                    &a8, &a9, &a10, &a11, &a12, &a13};
    hipLaunchCooperativeKernel(fused_kernel, dim3(256), dim3(1024), args, 0, stream);
}

// Round 15
// 813.369 us; speedup vs baseline: 1.2038x; 1.2038x over previous
//
#include <hip/hip_runtime.h>
#include <hip/hip_bf16.h>
#include <hip/hip_cooperative_groups.h>

namespace cg = cooperative_groups;

#define BB 32
#define LL 64
#define EE 1024
#define HH 128
#define VV 32000

typedef unsigned short u16;
typedef unsigned long long u64;
typedef __attribute__((ext_vector_type(8))) short bf16x8;
typedef __attribute__((ext_vector_type(8))) unsigned short u16x8;
typedef __attribute__((ext_vector_type(4))) float f32x4;

#define LOG2E 1.4426950408889634f
#define C2T   2.8853900817779268f   // 2*log2(e)

// output element offsets (return order: logits, c_fin, h_fin, alphas)
#define OFF_C ((size_t)BB * LL * VV)
#define OFF_H (OFF_C + (size_t)BB * HH)
#define OFF_A (OFF_H + (size_t)BB * HH)

// ws byte offsets
#define WS_ENCT 0                    // 8,388,608 B u16 encT [b][h][e] C2T-prescaled
#define WS_HS   ((size_t)8388608)    // 524,288 B bf16
#define WS_GX   ((size_t)8912896)    // 4,194,304 B f32
#define WS_PAYU ((size_t)13107200)   // 532,480 B u64 [32][8][2][130]
#define WS_PAYG ((size_t)13639680)   // 262,144 B u64 [32][8][2][64]
#define WS_WT   ((size_t)13901824)   // 8,192,000 B u16 w_softT
#define WS_DFL  ((size_t)22093824)   // 4 B detect flag
#define WS_NEED ((size_t)22093828)

#define PAYU_WORDS (32 * 8 * 2 * 130)   // 66,560
#define PAYG_WORDS (32 * 8 * 2 * 64)    // 32,768
#define PAY_TOTAL  (PAYU_WORDS + PAYG_WORDS)   // 99,328

// mega-prep role ranges (256 threads per block)
#define RESET_BLKS ((PAY_TOTAL + 255) / 256)   // 388
#define GX_BLKS    128
#define ENC_BLKS   (16 * BB)                   // 512
#define TW_BLKS    ((VV / 32) * 4)             // 4000
#define PREP_BLKS  (RESET_BLKS + GX_BLKS + ENC_BLKS + TW_BLKS)

__device__ __forceinline__ float bf2f(u16 u) {
    union { unsigned int i; float f; } v; v.i = ((unsigned int)u) << 16; return v.f;
}
__device__ __forceinline__ u16 f2bf(float f) {
    union { float f; unsigned int i; } v; v.f = f;
    unsigned int x = v.i;
    return (u16)((x + 0x7FFFu + ((x >> 16) & 1u)) >> 16);
}
__device__ __forceinline__ float ldf(const void* p, size_t i, int f32) {
    if (f32) return ((const float*)p)[i];
    return bf2f(((const u16*)p)[i]);
}
__device__ __forceinline__ void stout(void* p, size_t i, float v, int f32) {
    if (f32) ((float*)p)[i] = v;
    else ((u16*)p)[i] = f2bf(v);
}
__device__ __forceinline__ float sigm(float x) {
    return __builtin_amdgcn_rcpf(1.f + __builtin_amdgcn_exp2f(-x * LOG2E));
}
__device__ __forceinline__ float tanh_fast(float x) {
    return 1.f - 2.f * __builtin_amdgcn_rcpf(__builtin_amdgcn_exp2f(x * C2T) + 1.f);
}

// ---- mega-prep: reset + detect + gatesx + encproj + w_soft transpose -----
// (byte-identical to round 13, proven)
__global__ __launch_bounds__(256) void megaprep_kernel(
    const int* __restrict__ sent, const void* __restrict__ w_emb,
    const void* __restrict__ w_lstm, const void* __restrict__ enc_out,
    const void* __restrict__ V, const void* __restrict__ w_soft,
    float* __restrict__ gx, u16* __restrict__ encT, u16* __restrict__ wT,
    u64* __restrict__ pay, int* __restrict__ flag)
{
    const int blk = blockIdx.x;
    const int tid = threadIdx.x;
    __shared__ float smem[16384];              // 64KB, aliased per role
    __shared__ int dcnt[4];

    if (blk < RESET_BLKS) {
        int i = blk * 256 + tid;
        if (i < PAY_TOTAL) pay[i] = 0ull;
        if (blk == 0) {
            float a = fabsf(bf2f((u16)(((const unsigned int*)w_emb)[tid] & 0xFFFFu)));
            unsigned long long m = __ballot(a > 1e-4f && a < 0.5f);
            if ((tid & 63) == 0) dcnt[tid >> 6] = __popcll(m);
            __syncthreads();
            if (tid == 0)
                *flag = (dcnt[0] + dcnt[1] + dcnt[2] + dcnt[3] > 128) ? 1 : 0;
        }
        return;
    }
    float da = fabsf(bf2f((u16)(((const unsigned int*)w_emb)[tid] & 0xFFFFu)));
    unsigned long long dm = __ballot(da > 1e-4f && da < 0.5f);
    if ((tid & 63) == 0) dcnt[tid >> 6] = __popcll(dm);
    __syncthreads();
    const int isf32 = !(dcnt[0] + dcnt[1] + dcnt[2] + dcnt[3] > 128);
    __syncthreads();

    if (blk < RESET_BLKS + GX_BLKS) {
        int row0 = (blk - RESET_BLKS) * 16;
        float (*xr)[128] = (float(*)[128])smem;
        for (int i = tid; i < 2048; i += 256) {
            int r = i >> 7, col = i & 127;
            int id = sent[row0 + r];
            xr[r][col] = ldf(w_emb, (size_t)id * HH + col, isf32);
        }
        __syncthreads();
        int c0 = tid, c1 = tid + 256;
        float a0[16], a1[16];
        #pragma unroll
        for (int r = 0; r < 16; ++r) { a0[r] = 0.f; a1[r] = 0.f; }
        for (int kk = 0; kk < 128; ++kk) {
            float w0, w1;
            if (isf32) {
                w0 = ((const float*)w_lstm)[(size_t)kk * 512 + c0];
                w1 = ((const float*)w_lstm)[(size_t)kk * 512 + c1];
            } else {
                w0 = bf2f(((const u16*)w_lstm)[(size_t)kk * 512 + c0]);
                w1 = bf2f(((const u16*)w_lstm)[(size_t)kk * 512 + c1]);
            }
            #pragma unroll
            for (int r = 0; r < 16; ++r) {
                a0[r] += xr[r][kk] * w0;
                a1[r] += xr[r][kk] * w1;
            }
        }
        #pragma unroll
        for (int r = 0; r < 16; ++r) {
            gx[(size_t)(row0 + r) * 512 + c0] = a0[r];
            gx[(size_t)(row0 + r) * 512 + c1] = a1[r];
        }
        return;
    }
    if (blk < RESET_BLKS + GX_BLKS + ENC_BLKS) {
        int idx = blk - RESET_BLKS - GX_BLKS;
        int b = idx >> 4;
        int e0 = (idx & 15) * 64;
        float (*ve)[128] = (float(*)[128])smem;
        for (int i = tid; i < HH * HH; i += 256)
            ve[i >> 7][i & 127] = ldf(V, i, isf32);
        __syncthreads();
        int e = e0 + (tid & 63);
        int hb = (tid >> 6) * 32;
        size_t rowbase = ((size_t)b * EE + e) * HH;
        float acc[32];
        #pragma unroll
        for (int i = 0; i < 32; ++i) acc[i] = 0.f;
        for (int k0 = 0; k0 < HH; k0 += 16) {
            float ef[16];
            #pragma unroll
            for (int i = 0; i < 16; ++i) ef[i] = ldf(enc_out, rowbase + k0 + i, isf32);
            #pragma unroll
            for (int hh = 0; hh < 32; ++hh) {
                float a = acc[hh];
                #pragma unroll
                for (int kk = 0; kk < 16; ++kk)
                    a += ef[kk] * ve[k0 + kk][hb + hh];
                acc[hh] = a;
            }
        }
        u16* outp = encT + ((size_t)b * HH) * EE + e;   // [b][h][e]
        #pragma unroll
        for (int hh = 0; hh < 32; ++hh)
            outp[(size_t)(hh + hb) * EE] = f2bf(acc[hh] * C2T);
        return;
    }
    // w_softT = transpose(w_soft) : (VV, HH) bf16
    {
        int idx = blk - RESET_BLKS - GX_BLKS - ENC_BLKS;
        int n0 = (idx >> 2) * 32;
        int k0 = (idx & 3) * 32;
        u16 (*tile)[33] = (u16(*)[33])smem;
        int tx = tid & 31, ty0 = tid >> 5;
        #pragma unroll
        for (int i = 0; i < 4; ++i) {
            int ty = ty0 + i * 8;
            tile[ty][tx] = f2bf(ldf(w_soft, (size_t)(k0 + ty) * VV + n0 + tx, isf32));
        }
        __syncthreads();
        #pragma unroll
        for (int i = 0; i < 4; ++i) {
            int ty = ty0 + i * 8;
            wT[(size_t)(n0 + ty) * HH + k0 + tx] = tile[tx][ty];
        }
    }
}

// ---- cooperative: scan (byte-identical R13, 541us) + grid sync + logits --
__global__ __launch_bounds__(1024) void scan_logits_kernel(
    const void* __restrict__ init_c, const void* __restrict__ init_h,
    const void* __restrict__ enc_out, const void* __restrict__ w_lstm,
    const void* __restrict__ V, const u16* __restrict__ encTg16,
    const float* __restrict__ gx, u16* __restrict__ hs_bf,
    void* __restrict__ out, u64* __restrict__ payu, u64* __restrict__ payg,
    const u16* __restrict__ wT, const int* __restrict__ flagp)
{
    const int isf32 = !flagp[0];
    const int bid = blockIdx.x;
    const int b = bid & 31, k = bid >> 5;      // 8 partners, same XCD
    const int tid = threadIdx.x;

    __shared__ u16   encTl16[128][128];        // 32KB bf16, C2T-prescaled [h][e]
    __shared__ float encF[128][128];           // 64KB f32 enc slice [e][h]
    __shared__ u16   wrec16[64 * 128];         // 16KB bf16 [col_local][k]
    __shared__ float gall[512];
    __shared__ float harr[128], cst[128], hnew[128], hvC[128];
    __shared__ float dred[8][128];
    __shared__ float sc[128];
    __shared__ float exch[8][130];
    __shared__ float redw[2], redw2[2];
    __shared__ float m_s, s_s;

    // ---- one-time staging ----
    for (int i = tid; i < 128 * 128; i += 1024) {
        int h = i >> 7, e = i & 127;
        encTl16[h][e] = encTg16[(size_t)(b * 128 + h) * EE + k * 128 + e];
    }
    for (int i = tid; i < 128 * 128; i += 1024) {
        int e = i >> 7, hh = i & 127;
        encF[e][hh] = ldf(enc_out, ((size_t)b * EE + k * 128 + e) * HH + hh, isf32);
    }
    for (int i = tid; i < 64 * 128; i += 1024) {
        int c = i >> 7, kk = i & 127;
        wrec16[c * 128 + kk] = f2bf(ldf(w_lstm, (size_t)(HH + kk) * 512 + k * 64 + c, isf32));
    }
    if (tid < 128) {
        cst[tid]  = ldf(init_c, (size_t)b * HH + tid, isf32);
        harr[tid] = ldf(init_h, (size_t)b * HH + tid, isf32);
    }
    __syncthreads();

    u64* mypu = payu + (size_t)(b * 8 + k) * 2 * 130;
    u64* mypg = payg + (size_t)(b * 8 + k) * 2 * 64;

    for (int t = 0; t < LL; ++t) {
        const unsigned int want = (unsigned int)(t + 1);
        float g0 = 0.f, g1 = 0.f, g2 = 0.f, g3 = 0.f;
        if (tid < 128) {
            const float* gxr = gx + (size_t)(b * LL + t) * 512;
            g0 = gxr[tid]; g1 = gxr[128 + tid]; g2 = gxr[256 + tid]; g3 = gxr[384 + tid];
        }
        // A: this block's 64 gate cols; 16 lanes per col, shfl butterfly
        {
            int colL = tid >> 4, kc = tid & 15;
            const bf16x8 wv = *(const bf16x8*)&wrec16[colL * 128 + kc * 8];
            float acc = 0.f;
            #pragma unroll
            for (int j = 0; j < 8; ++j)
                acc = __builtin_fmaf(harr[kc * 8 + j], bf2f((u16)wv[j]), acc);
            acc += __shfl_xor(acc, 1);
            acc += __shfl_xor(acc, 2);
            acc += __shfl_xor(acc, 4);
            acc += __shfl_xor(acc, 8);
            if (kc == 0) {
                gall[(k << 6) + colL] = acc;
                union { float f; unsigned int u; } cv; cv.f = acc;
                u64 w = ((u64)want << 32) | (u64)cv.u;
                __hip_atomic_store(&mypg[(size_t)(t & 1) * 64 + colL], w,
                                   __ATOMIC_RELAXED, __HIP_MEMORY_SCOPE_AGENT);
            }
        }
        if (tid < 448) {
            int qq = tid >> 6;
            int q = qq + (qq >= k ? 1 : 0);
            int idx = tid & 63;
            const u64* qp = payg + ((size_t)(b * 8 + q) * 2 + (t & 1)) * 64 + idx;
            u64 w = __hip_atomic_load(qp, __ATOMIC_RELAXED, __HIP_MEMORY_SCOPE_AGENT);
            int cnt = 0;
            while ((unsigned int)(w >> 32) != want) {
                __builtin_amdgcn_s_sleep(1);
                w = __hip_atomic_load(qp, __ATOMIC_RELAXED, __HIP_MEMORY_SCOPE_AGENT);
                if (++cnt > (1 << 20)) break;   // fail visibly, never hang
            }
            union { unsigned int u; float f; } cv; cv.u = (unsigned int)(w & 0xFFFFFFFFu);
            gall[q * 64 + idx] = cv.f;
        }
        __syncthreads();                                   // (1)
        if (tid < 128) {
            float gi = g0 + gall[tid];
            float gf = g1 + gall[128 + tid];
            float go = g2 + gall[256 + tid];
            float gg = g3 + gall[384 + tid];
            float c_new = sigm(gf) * cst[tid] + sigm(gi) * tanh_fast(gg);
            cst[tid] = c_new;
            hnew[tid] = sigm(go) * tanh_fast(c_new);
        }
        __syncthreads();                                   // (2)
        // C: hv[h] = h_new . V_h[:,h] (L2-hot 64KB, shared by whole XCD)
        {
            int h = tid & 127, jc = tid >> 7;
            float p = 0.f;
            if (isf32) {
                const float* vp = (const float*)V + (size_t)(HH + jc * 16) * HH + h;
                #pragma unroll
                for (int j = 0; j < 16; ++j)
                    p += hnew[jc * 16 + j] * vp[(size_t)j * HH];
            } else {
                const u16* vp = (const u16*)V + (size_t)(HH + jc * 16) * HH + h;
                #pragma unroll
                for (int j = 0; j < 16; ++j)
                    p += hnew[jc * 16 + j] * bf2f(vp[(size_t)j * HH]);
            }
            dred[jc][h] = p;
        }
        __syncthreads();                                   // (3)
        if (tid < 128) {
            float v = 0.f;
            #pragma unroll
            for (int s = 0; s < 8; ++s) v += dred[s][tid];
            hvC[tid] = v * C2T;
        }
        __syncthreads();                                   // (4)
        // D: partial tanh sums over own 128-e slice (LDS bf16)
        {
            int e = tid & 127, hc = tid >> 7;
            float sumr = 0.f;
            #pragma unroll
            for (int j = 0; j < 16; ++j) {
                int h = hc * 16 + j;
                float a = bf2f(encTl16[h][e]) + hvC[h];
                sumr += __builtin_amdgcn_rcpf(__builtin_amdgcn_exp2f(a) + 1.f);
            }
            dred[hc][e] = sumr;
        }
        __syncthreads();                                   // (5)
        // E: local scores + local softmax stats
        float s_e = 0.f, p_reg = 0.f;
        if (tid < 128) {
            float sr = 0.f;
            #pragma unroll
            for (int s = 0; s < 8; ++s) sr += dred[s][tid];
            s_e = 128.f - 2.f * sr;
            float m = s_e;
            #pragma unroll
            for (int off = 32; off; off >>= 1) m = fmaxf(m, __shfl_xor(m, off));
            if ((tid & 63) == 0) redw[tid >> 6] = m;
        }
        __syncthreads();                                   // (6)
        if (tid < 128) {
            float mloc = fmaxf(redw[0], redw[1]);
            p_reg = __builtin_amdgcn_exp2f((s_e - mloc) * LOG2E);
            sc[tid] = p_reg;
            float s = p_reg;
            #pragma unroll
            for (int off = 32; off; off >>= 1) s += __shfl_xor(s, off);
            if ((tid & 63) == 0) redw2[tid >> 6] = s;
            if (tid == 0) m_s = mloc;
        }
        __syncthreads();                                   // (7)
        if (tid == 0) s_s = redw2[0] + redw2[1];
        // F: partial unnormalized context from LDS enc slice (f32, exact)
        {
            int h = tid & 127, ec = tid >> 7;
            float p = 0.f;
            #pragma unroll
            for (int j = 0; j < 16; ++j)
                p += sc[ec * 16 + j] * encF[ec * 16 + j][h];
            dred[ec][h] = p;
        }
        __syncthreads();                                   // (8)
        float Uv = 0.f;
        if (tid < 128) {
            #pragma unroll
            for (int s = 0; s < 8; ++s) Uv += dred[s][tid];
        }
        {
            u64* pp = mypu + (size_t)(t & 1) * 130;
            if (tid < 130) {
                float val = (tid < 128) ? Uv : ((tid == 128) ? m_s : s_s);
                union { float f; unsigned int u; } cv; cv.f = val;
                u64 w = ((u64)want << 32) | (u64)cv.u;
                __hip_atomic_store(&pp[tid], w, __ATOMIC_RELAXED, __HIP_MEMORY_SCOPE_AGENT);
                exch[k][tid] = val;
            }
        }
        if (tid < 910) {
            int qq = tid / 130;
            int q = qq + (qq >= k ? 1 : 0);
            int idx = tid - qq * 130;
            const u64* qp = payu + ((size_t)(b * 8 + q) * 2 + (t & 1)) * 130 + idx;
            u64 w = __hip_atomic_load(qp, __ATOMIC_RELAXED, __HIP_MEMORY_SCOPE_AGENT);
            int cnt = 0;
            while ((unsigned int)(w >> 32) != want) {
                __builtin_amdgcn_s_sleep(1);
                w = __hip_atomic_load(qp, __ATOMIC_RELAXED, __HIP_MEMORY_SCOPE_AGENT);
                if (++cnt > (1 << 20)) break;   // fail visibly, never hang
            }
            union { unsigned int u; float f; } cv; cv.u = (unsigned int)(w & 0xFFFFFFFFu);
            exch[q][idx] = cv.f;
        }
        __syncthreads();                                   // (9)
        if (tid < 128) {
            float M = exch[0][128];
            #pragma unroll
            for (int q = 1; q < 8; ++q) M = fmaxf(M, exch[q][128]);
            float St = 0.f, ch = 0.f;
            #pragma unroll
            for (int q = 0; q < 8; ++q) {
                float w = __builtin_amdgcn_exp2f((exch[q][128] - M) * LOG2E);
                St += w * exch[q][129];
                ch += w * exch[q][tid];
            }
            float rS = __builtin_amdgcn_rcpf(St);
            float ctx = ch * rS;
            harr[tid] = ctx;
            float al = p_reg * __builtin_amdgcn_exp2f((m_s - M) * LOG2E) * rS;
            stout(out, OFF_A + (size_t)(b * LL + t) * EE + k * 128 + tid, al, isf32);
            if (k == 0) {
                hs_bf[(size_t)(b * LL + t) * HH + tid] = f2bf(ctx);
                if (t == LL - 1) {
                    stout(out, OFF_H + (size_t)b * HH + tid, ctx, isf32);
                    stout(out, OFF_C + (size_t)b * HH + tid, cst[tid], isf32);
                }
            }
        }
        __syncthreads();                                   // (10)
    }

    __threadfence();
    cg::this_grid().sync();                    // ---- grid barrier ----

    // ======== LOGITS: hs @ w_soft via wT (proven R13 microkernel) ========
    {
        const int wgl = bid * 16 + (tid >> 6);        // wave 0..4095
        const int lane = tid & 63;
        const int lr = lane & 15, lh = lane >> 4;
        for (int task = wgl; task < 64000; task += 4096) {
            int nx = task >> 6, my = task & 63;
            int n0 = nx * 32, m0 = my * 32;
            f32x4 acc00 = {0.f, 0.f, 0.f, 0.f}, acc01 = acc00, acc10 = acc00, acc11 = acc00;
            const u16* a0p = hs_bf + (size_t)(m0 + lr) * HH + lh * 8;
            const u16* a1p = a0p + (size_t)16 * HH;
            const u16* b0p = wT + (size_t)(n0 + lr) * HH + lh * 8;
            const u16* b1p = b0p + (size_t)16 * HH;
            #pragma unroll
            for (int ks = 0; ks < 4; ++ks) {
                bf16x8 a0 = *(const bf16x8*)(a0p + ks * 32);
                bf16x8 a1 = *(const bf16x8*)(a1p + ks * 32);
                bf16x8 b0 = *(const bf16x8*)(b0p + ks * 32);
                bf16x8 b1 = *(const bf16x8*)(b1p + ks * 32);
                acc00 = __builtin_amdgcn_mfma_f32_16x16x32_bf16(a0, b0, acc00, 0, 0, 0);
                acc01 = __builtin_amdgcn_mfma_f32_16x16x32_bf16(a0, b1, acc01, 0, 0, 0);
                acc10 = __builtin_amdgcn_mfma_f32_16x16x32_bf16(a1, b0, acc10, 0, 0, 0);
                acc11 = __builtin_amdgcn_mfma_f32_16x16x32_bf16(a1, b1, acc11, 0, 0, 0);
            }
            size_t base0 = (size_t)(m0 + lh * 4) * VV + n0;
            size_t base1 = (size_t)(m0 + 16 + lh * 4) * VV + n0;
            #pragma unroll
            for (int r = 0; r < 4; ++r) {
                stout(out, base0 + (size_t)r * VV + lr,      acc00[r], isf32);
                stout(out, base0 + (size_t)r * VV + 16 + lr, acc01[r], isf32);
                stout(out, base1 + (size_t)r * VV + lr,      acc10[r], isf32);
                stout(out, base1 + (size_t)r * VV + 16 + lr, acc11[r], isf32);
            }
        }
    }
}

extern "C" void kernel_launch(void* const* d_in, const int* in_sizes, int n_in,
                              void* d_out, int out_size, void* d_ws, size_t ws_size,
                              hipStream_t stream)
{
    (void)in_sizes; (void)n_in; (void)out_size;
    if (ws_size < WS_NEED) return;

    const int* sent     = (const int*)d_in[0];
    const void* init_c  = d_in[1];
    const void* init_h  = d_in[2];
    const void* enc_out = d_in[3];
    const void* w_emb   = d_in[4];
    const void* w_lstm  = d_in[5];
    const void* w_soft  = d_in[6];
    const void* V       = d_in[7];

    char* ws = (char*)d_ws;
    u16*   encT  = (u16*)(ws + WS_ENCT);
    u16*   hs    = (u16*)(ws + WS_HS);
    float* gx    = (float*)(ws + WS_GX);
    u64*   payu  = (u64*)(ws + WS_PAYU);
    u64*   payg  = (u64*)(ws + WS_PAYG);
    u16*   wT    = (u16*)(ws + WS_WT);
    int*   dflag = (int*)(ws + WS_DFL);

    hipLaunchKernelGGL(megaprep_kernel, dim3(PREP_BLKS), dim3(256), 0, stream,
                       sent, w_emb, w_lstm, enc_out, V, w_soft,
                       gx, encT, wT, payu, dflag);

    {
        const void* a0 = init_c; const void* a1 = init_h; const void* a2 = enc_out;
        const void* a3 = w_lstm; const void* a4 = V; const u16* a5 = encT;
        const float* a6 = gx; u16* a7 = hs; void* a8 = d_out;
        u64* a9 = payu; u64* a10 = payg; const u16* a11 = wT; const int* a12 = dflag;
        void* args[] = {&a0, &a1, &a2, &a3, &a4, &a5, &a6, &a7, &a8, &a9, &a10, &a11, &a12};
        hipLaunchCooperativeKernel(scan_logits_kernel, dim3(256), dim3(1024), args, 0, stream);
    }
}

// Round 16
// 742.040 us; speedup vs baseline: 1.3195x; 1.0961x over previous
//
#include <hip/hip_runtime.h>
#include <hip/hip_bf16.h>

#define BB 32
#define LL 64
#define EE 1024
#define HH 128
#define VV 32000

typedef unsigned short u16;
typedef unsigned long long u64;
typedef __attribute__((ext_vector_type(8))) short bf16x8;
typedef __attribute__((ext_vector_type(8))) unsigned short u16x8;
typedef __attribute__((ext_vector_type(4))) float f32x4;

#define LOG2E 1.4426950408889634f
#define C2T   2.8853900817779268f   // 2*log2(e)

// output element offsets (return order: logits, c_fin, h_fin, alphas)
#define OFF_C ((size_t)BB * LL * VV)
#define OFF_H (OFF_C + (size_t)BB * HH)
#define OFF_A (OFF_H + (size_t)BB * HH)

// ws byte offsets
#define WS_ENCT 0                    // 8,388,608 B u16 encT [b][h][e] C2T-prescaled
#define WS_HS   ((size_t)8388608)    // 524,288 B bf16
#define WS_GX   ((size_t)8912896)    // 4,194,304 B f32
#define WS_PAYU ((size_t)13107200)   // 532,480 B u64 [32][8][2][130]
#define WS_PAYG ((size_t)13639680)   // 262,144 B u64 [32][8][2][64]
#define WS_WT   ((size_t)13901824)   // 8,192,000 B u16 w_softT
#define WS_DFL  ((size_t)22093824)   // 4 B detect flag
#define WS_NEED ((size_t)22093828)

#define PAYU_WORDS (32 * 8 * 2 * 130)   // 66,560
#define PAYG_WORDS (32 * 8 * 2 * 64)    // 32,768
#define PAY_TOTAL  (PAYU_WORDS + PAYG_WORDS)   // 99,328

// mega-prep role ranges (256 threads per block)
#define RESET_BLKS ((PAY_TOTAL + 255) / 256)   // 388
#define GX_BLKS    128
#define ENC_BLKS   (16 * BB)                   // 512
#define TW_BLKS    ((VV / 32) * 4)             // 4000
#define PREP_BLKS  (RESET_BLKS + GX_BLKS + ENC_BLKS + TW_BLKS)

__device__ __forceinline__ float bf2f(u16 u) {
    union { unsigned int i; float f; } v; v.i = ((unsigned int)u) << 16; return v.f;
}
__device__ __forceinline__ u16 f2bf(float f) {
    union { float f; unsigned int i; } v; v.f = f;
    unsigned int x = v.i;
    return (u16)((x + 0x7FFFu + ((x >> 16) & 1u)) >> 16);
}
__device__ __forceinline__ float ldf(const void* p, size_t i, int f32) {
    if (f32) return ((const float*)p)[i];
    return bf2f(((const u16*)p)[i]);
}
__device__ __forceinline__ void stout(void* p, size_t i, float v, int f32) {
    if (f32) ((float*)p)[i] = v;
    else ((u16*)p)[i] = f2bf(v);
}
__device__ __forceinline__ float sigm(float x) {
    return __builtin_amdgcn_rcpf(1.f + __builtin_amdgcn_exp2f(-x * LOG2E));
}
__device__ __forceinline__ float tanh_fast(float x) {
    return 1.f - 2.f * __builtin_amdgcn_rcpf(__builtin_amdgcn_exp2f(x * C2T) + 1.f);
}

// ---- mega-prep: reset + detect + gatesx + encproj + w_soft transpose -----
// (proven round 12/13)
__global__ __launch_bounds__(256) void megaprep_kernel(
    const int* __restrict__ sent, const void* __restrict__ w_emb,
    const void* __restrict__ w_lstm, const void* __restrict__ enc_out,
    const void* __restrict__ V, const void* __restrict__ w_soft,
    float* __restrict__ gx, u16* __restrict__ encT, u16* __restrict__ wT,
    u64* __restrict__ pay, int* __restrict__ flag)
{
    const int blk = blockIdx.x;
    const int tid = threadIdx.x;
    __shared__ float smem[16384];              // 64KB, aliased per role
    __shared__ int dcnt[4];

    if (blk < RESET_BLKS) {
        int i = blk * 256 + tid;
        if (i < PAY_TOTAL) pay[i] = 0ull;
        if (blk == 0) {
            float a = fabsf(bf2f((u16)(((const unsigned int*)w_emb)[tid] & 0xFFFFu)));
            unsigned long long m = __ballot(a > 1e-4f && a < 0.5f);
            if ((tid & 63) == 0) dcnt[tid >> 6] = __popcll(m);
            __syncthreads();
            if (tid == 0)
                *flag = (dcnt[0] + dcnt[1] + dcnt[2] + dcnt[3] > 128) ? 1 : 0;
        }
        return;
    }
    float da = fabsf(bf2f((u16)(((const unsigned int*)w_emb)[tid] & 0xFFFFu)));
    unsigned long long dm = __ballot(da > 1e-4f && da < 0.5f);
    if ((tid & 63) == 0) dcnt[tid >> 6] = __popcll(dm);
    __syncthreads();
    const int isf32 = !(dcnt[0] + dcnt[1] + dcnt[2] + dcnt[3] > 128);
    __syncthreads();

    if (blk < RESET_BLKS + GX_BLKS) {
        int row0 = (blk - RESET_BLKS) * 16;
        float (*xr)[128] = (float(*)[128])smem;
        for (int i = tid; i < 2048; i += 256) {
            int r = i >> 7, col = i & 127;
            int id = sent[row0 + r];
            xr[r][col] = ldf(w_emb, (size_t)id * HH + col, isf32);
        }
        __syncthreads();
        int c0 = tid, c1 = tid + 256;
        float a0[16], a1[16];
        #pragma unroll
        for (int r = 0; r < 16; ++r) { a0[r] = 0.f; a1[r] = 0.f; }
        for (int kk = 0; kk < 128; ++kk) {
            float w0, w1;
            if (isf32) {
                w0 = ((const float*)w_lstm)[(size_t)kk * 512 + c0];
                w1 = ((const float*)w_lstm)[(size_t)kk * 512 + c1];
            } else {
                w0 = bf2f(((const u16*)w_lstm)[(size_t)kk * 512 + c0]);
                w1 = bf2f(((const u16*)w_lstm)[(size_t)kk * 512 + c1]);
            }
            #pragma unroll
            for (int r = 0; r < 16; ++r) {
                a0[r] += xr[r][kk] * w0;
                a1[r] += xr[r][kk] * w1;
            }
        }
        #pragma unroll
        for (int r = 0; r < 16; ++r) {
            gx[(size_t)(row0 + r) * 512 + c0] = a0[r];
            gx[(size_t)(row0 + r) * 512 + c1] = a1[r];
        }
        return;
    }
    if (blk < RESET_BLKS + GX_BLKS + ENC_BLKS) {
        // encT[b][h][e] = bf16(C2T * enc[b][e][:] . V_e[:][h])
        int idx = blk - RESET_BLKS - GX_BLKS;
        int b = idx >> 4;
        int e0 = (idx & 15) * 64;
        float (*ve)[128] = (float(*)[128])smem;
        for (int i = tid; i < HH * HH; i += 256)
            ve[i >> 7][i & 127] = ldf(V, i, isf32);
        __syncthreads();
        int e = e0 + (tid & 63);
        int hb = (tid >> 6) * 32;
        size_t rowbase = ((size_t)b * EE + e) * HH;
        float acc[32];
        #pragma unroll
        for (int i = 0; i < 32; ++i) acc[i] = 0.f;
        for (int k0 = 0; k0 < HH; k0 += 16) {
            float ef[16];
            #pragma unroll
            for (int i = 0; i < 16; ++i) ef[i] = ldf(enc_out, rowbase + k0 + i, isf32);
            #pragma unroll
            for (int hh = 0; hh < 32; ++hh) {
                float a = acc[hh];
                #pragma unroll
                for (int kk = 0; kk < 16; ++kk)
                    a += ef[kk] * ve[k0 + kk][hb + hh];
                acc[hh] = a;
            }
        }
        u16* outp = encT + ((size_t)b * HH) * EE + e;   // [b][h][e]
        #pragma unroll
        for (int hh = 0; hh < 32; ++hh)
            outp[(size_t)(hh + hb) * EE] = f2bf(acc[hh] * C2T);
        return;
    }
    // w_softT = transpose(w_soft) : (VV, HH) bf16
    {
        int idx = blk - RESET_BLKS - GX_BLKS - ENC_BLKS;
        int n0 = (idx >> 2) * 32;
        int k0 = (idx & 3) * 32;
        u16 (*tile)[33] = (u16(*)[33])smem;
        int tx = tid & 31, ty0 = tid >> 5;
        #pragma unroll
        for (int i = 0; i < 4; ++i) {
            int ty = ty0 + i * 8;
            tile[ty][tx] = f2bf(ldf(w_soft, (size_t)(k0 + ty) * VV + n0 + tx, isf32));
        }
        __syncthreads();
        #pragma unroll
        for (int i = 0; i < 4; ++i) {
            int ty = ty0 + i * 8;
            wT[(size_t)(n0 + ty) * HH + k0 + tx] = tile[tx][ty];
        }
    }
}

// ---- cooperative scan: EXACT round-8/13 structure (reproduced 531-541us) --
__global__ __launch_bounds__(1024) void scan_kernel(
    const void* __restrict__ init_c, const void* __restrict__ init_h,
    const void* __restrict__ enc_out, const void* __restrict__ w_lstm,
    const void* __restrict__ V, const u16* __restrict__ encTg16,
    const float* __restrict__ gx, u16* __restrict__ hs_bf,
    void* __restrict__ out, u64* __restrict__ payu, u64* __restrict__ payg,
    const int* __restrict__ flagp)
{
    const int isf32 = !flagp[0];
    const int bid = blockIdx.x;
    const int b = bid & 31, k = bid >> 5;      // 8 partners, same XCD
    const int tid = threadIdx.x;

    __shared__ u16   encTl16[128][128];        // 32KB bf16, C2T-prescaled [h][e]
    __shared__ float encF[128][128];           // 64KB f32 enc slice [e][h]
    __shared__ u16   wrec16[64 * 128];         // 16KB bf16 [col_local][k]
    __shared__ float gall[512];
    __shared__ float harr[128], cst[128], hnew[128], hvC[128];
    __shared__ float dred[8][128];
    __shared__ float sc[128];
    __shared__ float exch[8][130];
    __shared__ float redw[2], redw2[2];
    __shared__ float m_s, s_s;

    // ---- one-time staging ----
    for (int i = tid; i < 128 * 128; i += 1024) {       // encT slice (bf16 copy)
        int h = i >> 7, e = i & 127;
        encTl16[h][e] = encTg16[(size_t)(b * 128 + h) * EE + k * 128 + e];
    }
    for (int i = tid; i < 128 * 128; i += 1024) {       // enc slice -> f32
        int e = i >> 7, hh = i & 127;
        encF[e][hh] = ldf(enc_out, ((size_t)b * EE + k * 128 + e) * HH + hh, isf32);
    }
    for (int i = tid; i < 64 * 128; i += 1024) {        // w_rec col slice -> bf16
        int c = i >> 7, kk = i & 127;
        wrec16[c * 128 + kk] = f2bf(ldf(w_lstm, (size_t)(HH + kk) * 512 + k * 64 + c, isf32));
    }
    if (tid < 128) {
        cst[tid]  = ldf(init_c, (size_t)b * HH + tid, isf32);
        harr[tid] = ldf(init_h, (size_t)b * HH + tid, isf32);
    }
    __syncthreads();

    u64* mypu = payu + (size_t)(b * 8 + k) * 2 * 130;
    u64* mypg = payg + (size_t)(b * 8 + k) * 2 * 64;

    for (int t = 0; t < LL; ++t) {
        const unsigned int want = (unsigned int)(t + 1);
        // prefetch gx words for B
        float g0 = 0.f, g1 = 0.f, g2 = 0.f, g3 = 0.f;
        if (tid < 128) {
            const float* gxr = gx + (size_t)(b * LL + t) * 512;
            g0 = gxr[tid]; g1 = gxr[128 + tid]; g2 = gxr[256 + tid]; g3 = gxr[384 + tid];
        }
        // A: this block's 64 gate cols; 16 lanes per col, shfl butterfly
        {
            int colL = tid >> 4, kc = tid & 15;
            const bf16x8 wv = *(const bf16x8*)&wrec16[colL * 128 + kc * 8];
            float acc = 0.f;
            #pragma unroll
            for (int j = 0; j < 8; ++j)
                acc = __builtin_fmaf(harr[kc * 8 + j], bf2f((u16)wv[j]), acc);
            acc += __shfl_xor(acc, 1);
            acc += __shfl_xor(acc, 2);
            acc += __shfl_xor(acc, 4);
            acc += __shfl_xor(acc, 8);
            if (kc == 0) {
                gall[(k << 6) + colL] = acc;
                union { float f; unsigned int u; } cv; cv.f = acc;
                u64 w = ((u64)want << 32) | (u64)cv.u;
                __hip_atomic_store(&mypg[(size_t)(t & 1) * 64 + colL], w,
                                   __ATOMIC_RELAXED, __HIP_MEMORY_SCOPE_AGENT);
            }
        }
        // poll partners' gate slices (448 words)
        if (tid < 448) {
            int qq = tid >> 6;
            int q = qq + (qq >= k ? 1 : 0);
            int idx = tid & 63;
            const u64* qp = payg + ((size_t)(b * 8 + q) * 2 + (t & 1)) * 64 + idx;
            u64 w = __hip_atomic_load(qp, __ATOMIC_RELAXED, __HIP_MEMORY_SCOPE_AGENT);
            int cnt = 0;
            while ((unsigned int)(w >> 32) != want) {
                __builtin_amdgcn_s_sleep(1);
                w = __hip_atomic_load(qp, __ATOMIC_RELAXED, __HIP_MEMORY_SCOPE_AGENT);
                if (++cnt > (1 << 20)) break;   // fail visibly, never hang
            }
            union { unsigned int u; float f; } cv; cv.u = (unsigned int)(w & 0xFFFFFFFFu);
            gall[q * 64 + idx] = cv.f;
        }
        __syncthreads();                                   // (1)
        // B: LSTM cell (gall identical across replicas)
        if (tid < 128) {
            float gi = g0 + gall[tid];
            float gf = g1 + gall[128 + tid];
            float go = g2 + gall[256 + tid];
            float gg = g3 + gall[384 + tid];
            float c_new = sigm(gf) * cst[tid] + sigm(gi) * tanh_fast(gg);
            cst[tid] = c_new;
            hnew[tid] = sigm(go) * tanh_fast(c_new);
        }
        __syncthreads();                                   // (2)
        // C: hv[h] = h_new . V_h[:,h] (L2-hot 64KB, shared by whole XCD)
        {
            int h = tid & 127, jc = tid >> 7;
            float p = 0.f;
            if (isf32) {
                const float* vp = (const float*)V + (size_t)(HH + jc * 16) * HH + h;
                #pragma unroll
                for (int j = 0; j < 16; ++j)
                    p += hnew[jc * 16 + j] * vp[(size_t)j * HH];
            } else {
                const u16* vp = (const u16*)V + (size_t)(HH + jc * 16) * HH + h;
                #pragma unroll
                for (int j = 0; j < 16; ++j)
                    p += hnew[jc * 16 + j] * bf2f(vp[(size_t)j * HH]);
            }
            dred[jc][h] = p;
        }
        __syncthreads();                                   // (3)
        if (tid < 128) {
            float v = 0.f;
            #pragma unroll
            for (int s = 0; s < 8; ++s) v += dred[s][tid];
            hvC[tid] = v * C2T;
        }
        __syncthreads();                                   // (4)
        // D: partial tanh sums over own 128-e slice (LDS bf16)
        {
            int e = tid & 127, hc = tid >> 7;
            float sumr = 0.f;
            #pragma unroll
            for (int j = 0; j < 16; ++j) {
                int h = hc * 16 + j;
                float a = bf2f(encTl16[h][e]) + hvC[h];
                sumr += __builtin_amdgcn_rcpf(__builtin_amdgcn_exp2f(a) + 1.f);
            }
            dred[hc][e] = sumr;
        }
        __syncthreads();                                   // (5)
        // E: local scores + local softmax stats
        float s_e = 0.f, p_reg = 0.f;
        if (tid < 128) {
            float sr = 0.f;
            #pragma unroll
            for (int s = 0; s < 8; ++s) sr += dred[s][tid];
            s_e = 128.f - 2.f * sr;
            float m = s_e;
            #pragma unroll
            for (int off = 32; off; off >>= 1) m = fmaxf(m, __shfl_xor(m, off));
            if ((tid & 63) == 0) redw[tid >> 6] = m;
        }
        __syncthreads();                                   // (6)
        if (tid < 128) {
            float mloc = fmaxf(redw[0], redw[1]);
            p_reg = __builtin_amdgcn_exp2f((s_e - mloc) * LOG2E);
            sc[tid] = p_reg;
            float s = p_reg;
            #pragma unroll
            for (int off = 32; off; off >>= 1) s += __shfl_xor(s, off);
            if ((tid & 63) == 0) redw2[tid >> 6] = s;
            if (tid == 0) m_s = mloc;
        }
        __syncthreads();                                   // (7)
        if (tid == 0) s_s = redw2[0] + redw2[1];
        // F: partial unnormalized context from LDS enc slice (f32, exact)
        {
            int h = tid & 127, ec = tid >> 7;
            float p = 0.f;
            #pragma unroll
            for (int j = 0; j < 16; ++j)
                p += sc[ec * 16 + j] * encF[ec * 16 + j][h];
            dred[ec][h] = p;
        }
        __syncthreads();                                   // (8)
        // reduce U and publish straight from registers
        float Uv = 0.f;
        if (tid < 128) {
            #pragma unroll
            for (int s = 0; s < 8; ++s) Uv += dred[s][tid];
        }
        {
            u64* pp = mypu + (size_t)(t & 1) * 130;
            if (tid < 130) {
                float val = (tid < 128) ? Uv : ((tid == 128) ? m_s : s_s);
                union { float f; unsigned int u; } cv; cv.f = val;
                u64 w = ((u64)want << 32) | (u64)cv.u;
                __hip_atomic_store(&pp[tid], w, __ATOMIC_RELAXED, __HIP_MEMORY_SCOPE_AGENT);
                exch[k][tid] = val;
            }
        }
        // poll partners' U payloads (910 threads, one word each)
        if (tid < 910) {
            int qq = tid / 130;
            int q = qq + (qq >= k ? 1 : 0);
            int idx = tid - qq * 130;
            const u64* qp = payu + ((size_t)(b * 8 + q) * 2 + (t & 1)) * 130 + idx;
            u64 w = __hip_atomic_load(qp, __ATOMIC_RELAXED, __HIP_MEMORY_SCOPE_AGENT);
            int cnt = 0;
            while ((unsigned int)(w >> 32) != want) {
                __builtin_amdgcn_s_sleep(1);
                w = __hip_atomic_load(qp, __ATOMIC_RELAXED, __HIP_MEMORY_SCOPE_AGENT);
                if (++cnt > (1 << 20)) break;   // fail visibly, never hang
            }
            union { unsigned int u; float f; } cv; cv.u = (unsigned int)(w & 0xFFFFFFFFu);
            exch[q][idx] = cv.f;
        }
        __syncthreads();                                   // (9)
        // combine in canonical order -> bit-identical context in all replicas
        if (tid < 128) {
            float M = exch[0][128];
            #pragma unroll
            for (int q = 1; q < 8; ++q) M = fmaxf(M, exch[q][128]);
            float St = 0.f, ch = 0.f;
            #pragma unroll
            for (int q = 0; q < 8; ++q) {
                float w = __builtin_amdgcn_exp2f((exch[q][128] - M) * LOG2E);
                St += w * exch[q][129];
                ch += w * exch[q][tid];
            }
            float rS = __builtin_amdgcn_rcpf(St);
            float ctx = ch * rS;
            harr[tid] = ctx;
            float al = p_reg * __builtin_amdgcn_exp2f((m_s - M) * LOG2E) * rS;
            stout(out, OFF_A + (size_t)(b * LL + t) * EE + k * 128 + tid, al, isf32);
            if (k == 0) {
                hs_bf[(size_t)(b * LL + t) * HH + tid] = f2bf(ctx);
                if (t == LL - 1) {
                    stout(out, OFF_H + (size_t)b * HH + tid, ctx, isf32);
                    stout(out, OFF_C + (size_t)b * HH + tid, cst[tid], isf32);
                }
            }
        }
        __syncthreads();                                   // (10)
    }
}

// ---- logits = hs @ w_soft : MFMA bf16 ------------------------------------
__global__ __launch_bounds__(256) void logits_gemm(
    const u16* __restrict__ hs, const u16* __restrict__ wT,
    void* __restrict__ out, const int* __restrict__ flagp)
{
    int isf32 = !flagp[0];
    int n0 = blockIdx.x * 32;
    int m0 = (blockIdx.y * 4 + (threadIdx.x >> 6)) * 32;
    int lane = threadIdx.x & 63;
    int lr = lane & 15, lh = lane >> 4;
    f32x4 acc00 = {0.f, 0.f, 0.f, 0.f}, acc01 = acc00, acc10 = acc00, acc11 = acc00;
    const u16* a0p = hs + (size_t)(m0 + lr) * HH + lh * 8;
    const u16* a1p = a0p + (size_t)16 * HH;
    const u16* b0p = wT + (size_t)(n0 + lr) * HH + lh * 8;
    const u16* b1p = b0p + (size_t)16 * HH;
    #pragma unroll
    for (int ks = 0; ks < 4; ++ks) {
        bf16x8 a0 = *(const bf16x8*)(a0p + ks * 32);
        bf16x8 a1 = *(const bf16x8*)(a1p + ks * 32);
        bf16x8 b0 = *(const bf16x8*)(b0p + ks * 32);
        bf16x8 b1 = *(const bf16x8*)(b1p + ks * 32);
        acc00 = __builtin_amdgcn_mfma_f32_16x16x32_bf16(a0, b0, acc00, 0, 0, 0);
        acc01 = __builtin_amdgcn_mfma_f32_16x16x32_bf16(a0, b1, acc01, 0, 0, 0);
        acc10 = __builtin_amdgcn_mfma_f32_16x16x32_bf16(a1, b0, acc10, 0, 0, 0);
        acc11 = __builtin_amdgcn_mfma_f32_16x16x32_bf16(a1, b1, acc11, 0, 0, 0);
    }
    size_t base0 = (size_t)(m0 + lh * 4) * VV + n0;
    size_t base1 = (size_t)(m0 + 16 + lh * 4) * VV + n0;
    #pragma unroll
    for (int r = 0; r < 4; ++r) {
        stout(out, base0 + (size_t)r * VV + lr,      acc00[r], isf32);
        stout(out, base0 + (size_t)r * VV + 16 + lr, acc01[r], isf32);
        stout(out, base1 + (size_t)r * VV + lr,      acc10[r], isf32);
        stout(out, base1 + (size_t)r * VV + 16 + lr, acc11[r], isf32);
    }
}

extern "C" void kernel_launch(void* const* d_in, const int* in_sizes, int n_in,
                              void* d_out, int out_size, void* d_ws, size_t ws_size,
                              hipStream_t stream)
{
    (void)in_sizes; (void)n_in; (void)out_size;
    if (ws_size < WS_NEED) return;

    const int* sent     = (const int*)d_in[0];
    const void* init_c  = d_in[1];
    const void* init_h  = d_in[2];
    const void* enc_out = d_in[3];
    const void* w_emb   = d_in[4];
    const void* w_lstm  = d_in[5];
    const void* w_soft  = d_in[6];
    const void* V       = d_in[7];

    char* ws = (char*)d_ws;
    u16*   encT  = (u16*)(ws + WS_ENCT);
    u16*   hs    = (u16*)(ws + WS_HS);
    float* gx    = (float*)(ws + WS_GX);
    u64*   payu  = (u64*)(ws + WS_PAYU);
    u64*   payg  = (u64*)(ws + WS_PAYG);
    u16*   wT    = (u16*)(ws + WS_WT);
    int*   dflag = (int*)(ws + WS_DFL);

    hipLaunchKernelGGL(megaprep_kernel, dim3(PREP_BLKS), dim3(256), 0, stream,
                       sent, w_emb, w_lstm, enc_out, V, w_soft,
                       gx, encT, wT, payu, dflag);

    {
        const void* a0 = init_c; const void* a1 = init_h; const void* a2 = enc_out;
        const void* a3 = w_lstm; const void* a4 = V; const u16* a5 = encT;
        const float* a6 = gx; u16* a7 = hs; void* a8 = d_out;
        u64* a9 = payu; u64* a10 = payg; const int* a11 = dflag;
        void* args[] = {&a0, &a1, &a2, &a3, &a4, &a5, &a6, &a7, &a8, &a9, &a10, &a11};
        hipLaunchCooperativeKernel(scan_kernel, dim3(256), dim3(1024), args, 0, stream);
    }

    hipLaunchKernelGGL(logits_gemm, dim3(VV / 32, 16), dim3(256), 0, stream, hs, wT, d_out, dflag);
}